// Round 1
// baseline (50.534 us; speedup 1.0000x reference)
//
#include <hip/hip_runtime.h>
#include <math.h>

constexpr int N_ITEMS = 512;
constexpr int TS      = 2048;    // TABLE_SAMPLES
constexpr int FULL    = 32768;
constexpr int PADDED  = 65536;
constexpr int NPAIR   = 512;     // BATCH * N_EVENTS
constexpr int SPLIT   = 4;       // blocks per pair in the main kernel

// ---- order-preserving float <-> uint encoding for atomic min/max ----
__device__ __forceinline__ unsigned fenc(float f) {
    unsigned u = __float_as_uint(f);
    return (u & 0x80000000u) ? ~u : (u | 0x80000000u);
}
__device__ __forceinline__ float fdec(unsigned e) {
    return __uint_as_float((e & 0x80000000u) ? (e & 0x7FFFFFFFu) : ~e);
}

// ws layout (bytes): [0..3] min_enc, [4..7] max_enc, [256..2303] idx[512], [2304..4351] w[512]
__global__ void k_init(unsigned* ws_u) {
    if (threadIdx.x == 0) { ws_u[0] = 0xFFFFFFFFu; ws_u[1] = 0u; }
}

__global__ void k_minmax(const float4* __restrict__ items4, unsigned* __restrict__ ws_u) {
    __shared__ unsigned smin[4], smax[4];
    int tid  = blockIdx.x * blockDim.x + threadIdx.x;
    int nthr = gridDim.x * blockDim.x;
    unsigned lmin = 0xFFFFFFFFu, lmax = 0u;
    const int NV = (N_ITEMS * TS) / 4;
    for (int i = tid; i < NV; i += nthr) {
        float4 v = items4[i];
        unsigned e0 = fenc(v.x), e1 = fenc(v.y), e2 = fenc(v.z), e3 = fenc(v.w);
        lmin = min(min(min(lmin, e0), min(e1, e2)), e3);
        lmax = max(max(max(lmax, e0), max(e1, e2)), e3);
    }
    // wave (64-lane) reduce
    for (int off = 32; off > 0; off >>= 1) {
        lmin = min(lmin, (unsigned)__shfl_xor((int)lmin, off));
        lmax = max(lmax, (unsigned)__shfl_xor((int)lmax, off));
    }
    int wave = threadIdx.x >> 6;
    if ((threadIdx.x & 63) == 0) { smin[wave] = lmin; smax[wave] = lmax; }
    __syncthreads();
    if (threadIdx.x == 0) {
        unsigned bmin = smin[0], bmax = smax[0];
        for (int wv = 1; wv < (int)(blockDim.x >> 6); ++wv) {
            bmin = min(bmin, smin[wv]);
            bmax = max(bmax, smax[wv]);
        }
        atomicMin(&ws_u[0], bmin);
        atomicMax(&ws_u[1], bmax);
    }
}

// one wave per (b,e) pair: argmax of logits + softmax-max weight = 1/sum(exp(x - xmax))
__global__ void __launch_bounds__(64) k_sel(const float* __restrict__ sel,
                                            int* __restrict__ ws_idx,
                                            float* __restrict__ ws_w) {
    int p    = blockIdx.x;
    int lane = threadIdx.x;
    const float* s = sel + (size_t)p * N_ITEMS;
    float x[8];
    float vmax = -INFINITY;
    int   imax = 0x7FFFFFFF;
    #pragma unroll
    for (int k = 0; k < 8; ++k) {
        int i = lane + k * 64;
        x[k] = s[i];
        if (x[k] > vmax) { vmax = x[k]; imax = i; }   // ascending i -> first occurrence kept
    }
    for (int off = 32; off > 0; off >>= 1) {
        float ov = __shfl_xor(vmax, off);
        int   oi = __shfl_xor(imax, off);
        if (ov > vmax || (ov == vmax && oi < imax)) { vmax = ov; imax = oi; }
    }
    float se = 0.0f;
    #pragma unroll
    for (int k = 0; k < 8; ++k) se += expf(x[k] - vmax);
    for (int off = 32; off > 0; off >>= 1) se += __shfl_xor(se, off);
    if (lane == 0) { ws_idx[p] = imax; ws_w[p] = 1.0f / se; }
}

// main: each block = one (pair, quarter). Stage normalized*w row in LDS, interp x16,
// multiply by noise, write amp chunk + zero pad chunk.
__global__ void __launch_bounds__(256) k_main(const float* __restrict__ items,
                                              const float* __restrict__ noise,
                                              const unsigned* __restrict__ ws_u,
                                              const int* __restrict__ ws_idx,
                                              const float* __restrict__ ws_w,
                                              float* __restrict__ out) {
    __shared__ float row[TS];
    int blk = blockIdx.x;
    int p = blk / SPLIT;
    int q = blk % SPLIT;

    float minv  = fdec(ws_u[0]);
    float maxv  = fdec(ws_u[1]);
    float denom = (maxv - minv) + 0.001f;
    int   idx   = ws_idx[p];
    float w     = ws_w[p];

    const float4* it4 = (const float4*)(items + (size_t)idx * TS);
    for (int v = threadIdx.x; v < TS / 4; v += 256) {
        float4 r = it4[v];
        row[v * 4 + 0] = (r.x - minv) / denom * w;
        row[v * 4 + 1] = (r.y - minv) / denom * w;
        row[v * 4 + 2] = (r.z - minv) / denom * w;
        row[v * 4 + 3] = (r.w - minv) / denom * w;
    }
    __syncthreads();

    constexpr int CHUNK = FULL / SPLIT;   // 8192
    const float4* nz4  = (const float4*)(noise + (size_t)p * FULL + (size_t)q * CHUNK);
    float4*       o4   = (float4*)(out + (size_t)p * PADDED + (size_t)q * CHUNK);
    float4*       pad4 = (float4*)(out + (size_t)p * PADDED + FULL + (size_t)q * CHUNK);
    int tbase = q * CHUNK;

    for (int v = threadIdx.x; v < CHUNK / 4; v += 256) {
        float4 nz = nz4[v];
        float4 o;
        int t0 = tbase + v * 4;
        #pragma unroll
        for (int j = 0; j < 4; ++j) {
            float pos = ((float)(t0 + j) + 0.5f) * 0.0625f - 0.5f;   // in_size/FULL = 1/16 exact
            pos = fminf(fmaxf(pos, 0.0f), (float)(TS - 1));
            int lo = (int)pos;                 // pos >= 0 -> trunc == floor
            int hi = min(lo + 1, TS - 1);
            float fr = pos - (float)lo;
            float amp = row[lo] * (1.0f - fr) + row[hi] * fr;
            ((float*)&o)[j] = amp * ((const float*)&nz)[j];
        }
        o4[v] = o;
    }

    float4 z = make_float4(0.f, 0.f, 0.f, 0.f);
    for (int v = threadIdx.x; v < CHUNK / 4; v += 256) {
        pad4[v] = z;
    }
}

extern "C" void kernel_launch(void* const* d_in, const int* in_sizes, int n_in,
                              void* d_out, int out_size, void* d_ws, size_t ws_size,
                              hipStream_t stream) {
    const float* sel   = (const float*)d_in[0];   // [8,64,512]
    const float* items = (const float*)d_in[1];   // [512,2048]
    const float* noise = (const float*)d_in[2];   // [8,64,32768]
    float* out = (float*)d_out;                   // [8,64,65536]

    unsigned* ws_u   = (unsigned*)d_ws;
    int*      ws_idx = (int*)((char*)d_ws + 256);
    float*    ws_w   = (float*)((char*)d_ws + 256 + NPAIR * 4);

    hipLaunchKernelGGL(k_init,   dim3(1),             dim3(64),  0, stream, ws_u);
    hipLaunchKernelGGL(k_minmax, dim3(256),           dim3(256), 0, stream,
                       (const float4*)items, ws_u);
    hipLaunchKernelGGL(k_sel,    dim3(NPAIR),         dim3(64),  0, stream,
                       sel, ws_idx, ws_w);
    hipLaunchKernelGGL(k_main,   dim3(NPAIR * SPLIT), dim3(256), 0, stream,
                       items, noise, ws_u, ws_idx, ws_w, out);
}

// Round 2
// 46.483 us; speedup vs baseline: 1.0872x; 1.0872x over previous
//
#include <hip/hip_runtime.h>
#include <math.h>

constexpr int N_ITEMS = 512;
constexpr int TS      = 2048;    // TABLE_SAMPLES
constexpr int FULL    = 32768;
constexpr int PADDED  = 65536;
constexpr int NPAIR   = 512;     // BATCH * N_EVENTS
constexpr int SPLIT   = 4;       // blocks per pair in the main kernel

using f4 = __attribute__((ext_vector_type(4))) float;

// ---- order-preserving float <-> uint encoding for min/max over partials ----
__device__ __forceinline__ unsigned fenc(float f) {
    unsigned u = __float_as_uint(f);
    return (u & 0x80000000u) ? ~u : (u | 0x80000000u);
}
__device__ __forceinline__ float fdec(unsigned e) {
    return __uint_as_float((e & 0x80000000u) ? (e & 0x7FFFFFFFu) : ~e);
}

// ws layout (bytes):
//   [0      .. 1023]  min partials, unsigned[256]
//   [1024   .. 2047]  max partials, unsigned[256]
//   [2048   .. 4095]  idx, int[512]
//   [4096   .. 6143]  w,   float[512]

// One kernel for all prep: blocks 0..255 -> items min/max partials,
// blocks 256..383 -> selection (4 pairs per block, one wave each).
__global__ void __launch_bounds__(256) k_prep(const f4* __restrict__ items4,
                                              const float* __restrict__ sel,
                                              unsigned* __restrict__ ws_min,
                                              unsigned* __restrict__ ws_max,
                                              int* __restrict__ ws_idx,
                                              float* __restrict__ ws_w) {
    __shared__ unsigned smin[4], smax[4];
    int blk = blockIdx.x;

    if (blk < 256) {
        // ---- min/max partial over 1/256 of the items table ----
        unsigned lmin = 0xFFFFFFFFu, lmax = 0u;
        const int NV = (N_ITEMS * TS) / 4;          // 262144 float4
        for (int i = blk * 256 + threadIdx.x; i < NV; i += 256 * 256) {
            f4 v = items4[i];
            unsigned e0 = fenc(v.x), e1 = fenc(v.y), e2 = fenc(v.z), e3 = fenc(v.w);
            lmin = min(min(min(lmin, e0), min(e1, e2)), e3);
            lmax = max(max(max(lmax, e0), max(e1, e2)), e3);
        }
        for (int off = 32; off > 0; off >>= 1) {
            lmin = min(lmin, (unsigned)__shfl_xor((int)lmin, off));
            lmax = max(lmax, (unsigned)__shfl_xor((int)lmax, off));
        }
        int wave = threadIdx.x >> 6;
        if ((threadIdx.x & 63) == 0) { smin[wave] = lmin; smax[wave] = lmax; }
        __syncthreads();
        if (threadIdx.x == 0) {
            ws_min[blk] = min(min(smin[0], smin[1]), min(smin[2], smin[3]));
            ws_max[blk] = max(max(smax[0], smax[1]), max(smax[2], smax[3]));
        }
    } else {
        // ---- sparse-softmax selection: 4 pairs per block, one wave each ----
        int p    = (blk - 256) * 4 + (threadIdx.x >> 6);
        int lane = threadIdx.x & 63;
        const float* s = sel + (size_t)p * N_ITEMS;
        float x[8];
        float vmax = -INFINITY;
        int   imax = 0x7FFFFFFF;
        #pragma unroll
        for (int k = 0; k < 8; ++k) {
            int i = lane + k * 64;
            x[k] = s[i];
            if (x[k] > vmax) { vmax = x[k]; imax = i; }  // ascending -> first occurrence
        }
        for (int off = 32; off > 0; off >>= 1) {
            float ov = __shfl_xor(vmax, off);
            int   oi = __shfl_xor(imax, off);
            if (ov > vmax || (ov == vmax && oi < imax)) { vmax = ov; imax = oi; }
        }
        float se = 0.0f;
        #pragma unroll
        for (int k = 0; k < 8; ++k) se += expf(x[k] - vmax);
        for (int off = 32; off > 0; off >>= 1) se += __shfl_xor(se, off);
        if (lane == 0) { ws_idx[p] = imax; ws_w[p] = 1.0f / se; }
    }
}

// main: each block = one (pair, quarter). Prologue reduces the 256 min/max
// partials (L2-hit) and stages the normalized*w row in LDS; body streams
// noise in and amp+pad out with non-temporal ops.
__global__ void __launch_bounds__(256) k_main(const float* __restrict__ items,
                                              const float* __restrict__ noise,
                                              const unsigned* __restrict__ ws_min,
                                              const unsigned* __restrict__ ws_max,
                                              const int* __restrict__ ws_idx,
                                              const float* __restrict__ ws_w,
                                              float* __restrict__ out) {
    __shared__ float row[TS];
    __shared__ unsigned sred[8];
    __shared__ float s_sb[2];

    int blk = blockIdx.x;
    int p   = blk >> 2;          // SPLIT = 4
    int q   = blk & 3;
    int tid = threadIdx.x;

    // issue the item-row loads early (latency hides under the reduction)
    int idx = ws_idx[p];
    const f4* it4 = (const f4*)(items + (size_t)idx * TS);
    f4 r0 = it4[tid];
    f4 r1 = it4[tid + 256];

    // reduce 256 min/max partials
    unsigned lmin = ws_min[tid], lmax = ws_max[tid];
    for (int off = 32; off > 0; off >>= 1) {
        lmin = min(lmin, (unsigned)__shfl_xor((int)lmin, off));
        lmax = max(lmax, (unsigned)__shfl_xor((int)lmax, off));
    }
    int wave = tid >> 6;
    if ((tid & 63) == 0) { sred[wave] = lmin; sred[4 + wave] = lmax; }
    __syncthreads();
    if (tid == 0) {
        unsigned m0 = min(min(sred[0], sred[1]), min(sred[2], sred[3]));
        unsigned m1 = max(max(sred[4], sred[5]), max(sred[6], sred[7]));
        float minv  = fdec(m0);
        float maxv  = fdec(m1);
        float denom = (maxv - minv) + 0.001f;
        float scale = ws_w[p] / denom;
        s_sb[0] = scale;
        s_sb[1] = -minv * scale;
    }
    __syncthreads();
    float scale = s_sb[0], bias = s_sb[1];

    row[tid * 4 + 0] = fmaf(r0.x, scale, bias);
    row[tid * 4 + 1] = fmaf(r0.y, scale, bias);
    row[tid * 4 + 2] = fmaf(r0.z, scale, bias);
    row[tid * 4 + 3] = fmaf(r0.w, scale, bias);
    row[(tid + 256) * 4 + 0] = fmaf(r1.x, scale, bias);
    row[(tid + 256) * 4 + 1] = fmaf(r1.y, scale, bias);
    row[(tid + 256) * 4 + 2] = fmaf(r1.z, scale, bias);
    row[(tid + 256) * 4 + 3] = fmaf(r1.w, scale, bias);
    __syncthreads();

    constexpr int CHUNK = FULL / SPLIT;   // 8192
    const f4* nz4  = (const f4*)(noise + (size_t)p * FULL + (size_t)q * CHUNK);
    f4*       o4   = (f4*)(out + (size_t)p * PADDED + (size_t)q * CHUNK);
    f4*       pad4 = (f4*)(out + (size_t)p * PADDED + FULL + (size_t)q * CHUNK);
    int tbase = q * CHUNK;

    f4 z = {0.f, 0.f, 0.f, 0.f};
    for (int v = tid; v < CHUNK / 4; v += 256) {
        f4 nz = __builtin_nontemporal_load(&nz4[v]);
        f4 o;
        int t0 = tbase + v * 4;
        #pragma unroll
        for (int j = 0; j < 4; ++j) {
            float pos = ((float)(t0 + j) + 0.5f) * 0.0625f - 0.5f;   // in/out = 1/16 exact
            pos = fminf(fmaxf(pos, 0.0f), (float)(TS - 1));
            int lo = (int)pos;                    // pos >= 0 -> trunc == floor
            int hi = min(lo + 1, TS - 1);
            float fr = pos - (float)lo;
            float amp = row[lo] * (1.0f - fr) + row[hi] * fr;
            o[j] = amp * nz[j];
        }
        __builtin_nontemporal_store(o, &o4[v]);
        __builtin_nontemporal_store(z, &pad4[v]);
    }
}

extern "C" void kernel_launch(void* const* d_in, const int* in_sizes, int n_in,
                              void* d_out, int out_size, void* d_ws, size_t ws_size,
                              hipStream_t stream) {
    const float* sel   = (const float*)d_in[0];   // [8,64,512]
    const float* items = (const float*)d_in[1];   // [512,2048]
    const float* noise = (const float*)d_in[2];   // [8,64,32768]
    float* out = (float*)d_out;                   // [8,64,65536]

    unsigned* ws_min = (unsigned*)d_ws;
    unsigned* ws_max = (unsigned*)((char*)d_ws + 1024);
    int*      ws_idx = (int*)((char*)d_ws + 2048);
    float*    ws_w   = (float*)((char*)d_ws + 4096);

    hipLaunchKernelGGL(k_prep, dim3(256 + NPAIR / 4), dim3(256), 0, stream,
                       (const f4*)items, sel, ws_min, ws_max, ws_idx, ws_w);
    hipLaunchKernelGGL(k_main, dim3(NPAIR * SPLIT), dim3(256), 0, stream,
                       items, noise, ws_min, ws_max, ws_idx, ws_w, out);
}

// Round 3
// 40.945 us; speedup vs baseline: 1.2342x; 1.1352x over previous
//
#include <hip/hip_runtime.h>
#include <math.h>

constexpr int N_ITEMS = 512;
constexpr int TS      = 2048;    // TABLE_SAMPLES
constexpr int FULL    = 32768;
constexpr int PADDED  = 65536;
constexpr int NPAIR   = 512;     // BATCH * N_EVENTS

using f4 = __attribute__((ext_vector_type(4))) float;

// ---- order-preserving float <-> uint encoding for min/max over partials ----
__device__ __forceinline__ unsigned fenc(float f) {
    unsigned u = __float_as_uint(f);
    return (u & 0x80000000u) ? ~u : (u | 0x80000000u);
}
__device__ __forceinline__ float fdec(unsigned e) {
    return __uint_as_float((e & 0x80000000u) ? (e & 0x7FFFFFFFu) : ~e);
}

// ws layout (bytes):
//   [0      .. 1023]  min partials, unsigned[256]
//   [1024   .. 2047]  max partials, unsigned[256]
//   [2048   .. 4095]  idx, int[512]
//   [4096   .. 6143]  w,   float[512]

// k_prep, grid = 1024 x 256:
//   every block   : nt-store 64 KB of the zero pad (its pair-half)
//   blocks 0..255 : min/max partials over 1/256 of the items table
//   blocks 256..383: sparse-softmax selection, 4 pairs per block (1 wave each)
__global__ void __launch_bounds__(256) k_prep(const f4* __restrict__ items4,
                                              const float* __restrict__ sel,
                                              unsigned* __restrict__ ws_min,
                                              unsigned* __restrict__ ws_max,
                                              int* __restrict__ ws_idx,
                                              float* __restrict__ ws_w,
                                              float* __restrict__ out) {
    __shared__ unsigned smin[4], smax[4];
    int blk = blockIdx.x;
    int tid = threadIdx.x;

    // ---- role work first: issue the tiny reads early ----
    if (blk < 256) {
        unsigned lmin = 0xFFFFFFFFu, lmax = 0u;
        const int NV = (N_ITEMS * TS) / 4;          // 262144 float4
        for (int i = blk * 256 + tid; i < NV; i += 256 * 256) {   // 4 iters
            f4 v = items4[i];
            unsigned e0 = fenc(v.x), e1 = fenc(v.y), e2 = fenc(v.z), e3 = fenc(v.w);
            lmin = min(min(min(lmin, e0), min(e1, e2)), e3);
            lmax = max(max(max(lmax, e0), max(e1, e2)), e3);
        }
        for (int off = 32; off > 0; off >>= 1) {
            lmin = min(lmin, (unsigned)__shfl_xor((int)lmin, off));
            lmax = max(lmax, (unsigned)__shfl_xor((int)lmax, off));
        }
        int wave = tid >> 6;
        if ((tid & 63) == 0) { smin[wave] = lmin; smax[wave] = lmax; }
        __syncthreads();
        if (tid == 0) {
            ws_min[blk] = min(min(smin[0], smin[1]), min(smin[2], smin[3]));
            ws_max[blk] = max(max(smax[0], smax[1]), max(smax[2], smax[3]));
        }
    } else if (blk < 384) {
        int p    = (blk - 256) * 4 + (tid >> 6);
        int lane = tid & 63;
        const float* s = sel + (size_t)p * N_ITEMS;
        float x[8];
        float vmax = -INFINITY;
        int   imax = 0x7FFFFFFF;
        #pragma unroll
        for (int k = 0; k < 8; ++k) {
            int i = lane + k * 64;
            x[k] = s[i];
            if (x[k] > vmax) { vmax = x[k]; imax = i; }  // ascending -> first occurrence
        }
        for (int off = 32; off > 0; off >>= 1) {
            float ov = __shfl_xor(vmax, off);
            int   oi = __shfl_xor(imax, off);
            if (ov > vmax || (ov == vmax && oi < imax)) { vmax = ov; imax = oi; }
        }
        float se = 0.0f;
        #pragma unroll
        for (int k = 0; k < 8; ++k) se += expf(x[k] - vmax);
        for (int off = 32; off > 0; off >>= 1) se += __shfl_xor(se, off);
        if (lane == 0) { ws_idx[p] = imax; ws_w[p] = 1.0f / se; }
    }

    // ---- every block: zero its pair-half of the pad region (nt, bypass L2) ----
    {
        int p = blk >> 1, h = blk & 1;
        f4* pad4 = (f4*)(out + (size_t)p * PADDED + FULL + (size_t)h * (PADDED - FULL) / 2);
        f4 z = {0.f, 0.f, 0.f, 0.f};
        #pragma unroll
        for (int v = 0; v < 16; ++v)                 // 16 * 256 * 16B = 64 KB
            __builtin_nontemporal_store(z, &pad4[tid + v * 256]);
    }
}

// k_main, grid = 1024 x 256: block = (pair, half). Prologue reduces the 256
// min/max partials (L2-hit) and stages the normalized*w row in LDS; body
// streams 16 float4 per thread: nt-load noise, interp, nt-store amp.
__global__ void __launch_bounds__(256) k_main(const float* __restrict__ items,
                                              const float* __restrict__ noise,
                                              const unsigned* __restrict__ ws_min,
                                              const unsigned* __restrict__ ws_max,
                                              const int* __restrict__ ws_idx,
                                              const float* __restrict__ ws_w,
                                              float* __restrict__ out) {
    __shared__ float row[TS];
    __shared__ unsigned sred[8];
    __shared__ float s_sb[2];

    int blk = blockIdx.x;
    int p   = blk >> 1;
    int q   = blk & 1;
    int tid = threadIdx.x;

    // issue the item-row loads early (latency hides under the reduction)
    int idx = ws_idx[p];
    const f4* it4 = (const f4*)(items + (size_t)idx * TS);
    f4 r0 = it4[tid];
    f4 r1 = it4[tid + 256];

    // reduce 256 min/max partials
    unsigned lmin = ws_min[tid], lmax = ws_max[tid];
    for (int off = 32; off > 0; off >>= 1) {
        lmin = min(lmin, (unsigned)__shfl_xor((int)lmin, off));
        lmax = max(lmax, (unsigned)__shfl_xor((int)lmax, off));
    }
    int wave = tid >> 6;
    if ((tid & 63) == 0) { sred[wave] = lmin; sred[4 + wave] = lmax; }
    __syncthreads();
    if (tid == 0) {
        unsigned m0 = min(min(sred[0], sred[1]), min(sred[2], sred[3]));
        unsigned m1 = max(max(sred[4], sred[5]), max(sred[6], sred[7]));
        float minv  = fdec(m0);
        float maxv  = fdec(m1);
        float denom = (maxv - minv) + 0.001f;
        float scale = ws_w[p] / denom;
        s_sb[0] = scale;
        s_sb[1] = -minv * scale;
    }
    __syncthreads();
    float scale = s_sb[0], bias = s_sb[1];

    row[tid * 4 + 0] = fmaf(r0.x, scale, bias);
    row[tid * 4 + 1] = fmaf(r0.y, scale, bias);
    row[tid * 4 + 2] = fmaf(r0.z, scale, bias);
    row[tid * 4 + 3] = fmaf(r0.w, scale, bias);
    row[(tid + 256) * 4 + 0] = fmaf(r1.x, scale, bias);
    row[(tid + 256) * 4 + 1] = fmaf(r1.y, scale, bias);
    row[(tid + 256) * 4 + 2] = fmaf(r1.z, scale, bias);
    row[(tid + 256) * 4 + 3] = fmaf(r1.w, scale, bias);
    __syncthreads();

    constexpr int CHUNK = FULL / 2;   // 16384
    const f4* nz4 = (const f4*)(noise + (size_t)p * FULL + (size_t)q * CHUNK);
    f4*       o4  = (f4*)(out + (size_t)p * PADDED + (size_t)q * CHUNK);
    int tbase = q * CHUNK;

    for (int v = tid; v < CHUNK / 4; v += 256) {     // 16 iters
        f4 nz = __builtin_nontemporal_load(&nz4[v]);
        f4 o;
        int t0 = tbase + v * 4;
        #pragma unroll
        for (int j = 0; j < 4; ++j) {
            float pos = ((float)(t0 + j) + 0.5f) * 0.0625f - 0.5f;   // in/out = 1/16 exact
            pos = fminf(fmaxf(pos, 0.0f), (float)(TS - 1));
            int lo = (int)pos;                    // pos >= 0 -> trunc == floor
            int hi = min(lo + 1, TS - 1);
            float fr = pos - (float)lo;
            float amp = row[lo] * (1.0f - fr) + row[hi] * fr;
            o[j] = amp * nz[j];
        }
        __builtin_nontemporal_store(o, &o4[v]);
    }
}

extern "C" void kernel_launch(void* const* d_in, const int* in_sizes, int n_in,
                              void* d_out, int out_size, void* d_ws, size_t ws_size,
                              hipStream_t stream) {
    const float* sel   = (const float*)d_in[0];   // [8,64,512]
    const float* items = (const float*)d_in[1];   // [512,2048]
    const float* noise = (const float*)d_in[2];   // [8,64,32768]
    float* out = (float*)d_out;                   // [8,64,65536]

    unsigned* ws_min = (unsigned*)d_ws;
    unsigned* ws_max = (unsigned*)((char*)d_ws + 1024);
    int*      ws_idx = (int*)((char*)d_ws + 2048);
    float*    ws_w   = (float*)((char*)d_ws + 4096);

    hipLaunchKernelGGL(k_prep, dim3(NPAIR * 2), dim3(256), 0, stream,
                       (const f4*)items, sel, ws_min, ws_max, ws_idx, ws_w, out);
    hipLaunchKernelGGL(k_main, dim3(NPAIR * 2), dim3(256), 0, stream,
                       items, noise, ws_min, ws_max, ws_idx, ws_w, out);
}